// Round 1
// baseline (408.500 us; speedup 1.0000x reference)
//
#include <hip/hip_runtime.h>
#include <hip/hip_fp16.h>
#include <math.h>

typedef unsigned short u16;
typedef _Float16 f16x8 __attribute__((ext_vector_type(8)));
typedef float f32x4 __attribute__((ext_vector_type(4)));

#define LOG2E 1.4426950408889634f

static __device__ __forceinline__ u16 f2h(float f) {
    _Float16 h = (_Float16)f;
    return __builtin_bit_cast(u16, h);
}

// ---------------- prep: x -> f16, row sum-of-squares ----------------
__global__ __launch_bounds__(256) void prep_x(const float* __restrict__ x,
                                              u16* __restrict__ xh,
                                              float* __restrict__ sq) {
    int wave = threadIdx.x >> 6, lane = threadIdx.x & 63;
    int row = blockIdx.x * 4 + wave;             // 0..8191
    const float2 v = *reinterpret_cast<const float2*>(x + (size_t)row * 128 + lane * 2);
    float ss = v.x * v.x + v.y * v.y;
#pragma unroll
    for (int m = 1; m < 64; m <<= 1) ss += __shfl_xor(ss, m, 64);
    unsigned int packed = (unsigned int)f2h(v.x) | ((unsigned int)f2h(v.y) << 16);
    *reinterpret_cast<unsigned int*>(xh + (size_t)row * 128 + lane * 2) = packed;
    if (lane == 0) sq[row] = ss;
}

// ---------------- prep: weight-normed W -> f16 (row-major [out][128]) ----------------
__global__ __launch_bounds__(64) void prep_w(const float* __restrict__ vq, const float* __restrict__ gq,
                                             const float* __restrict__ v1, const float* __restrict__ g1,
                                             const float* __restrict__ v2, const float* __restrict__ g2,
                                             u16* __restrict__ wq, u16* __restrict__ w1, u16* __restrict__ w2,
                                             float* __restrict__ accum) {
    int row = blockIdx.x, lane = threadIdx.x;
    if (row == 0 && lane == 0) accum[0] = 0.f;
    const float* src; float gv; u16* dst; int r;
    if (row < 384)      { r = row;       src = vq + (size_t)r * 128; gv = gq[r]; dst = wq + (size_t)r * 128; }
    else if (row < 512) { r = row - 384; src = v1 + (size_t)r * 128; gv = g1[r]; dst = w1 + (size_t)r * 128; }
    else                { r = row - 512; src = v2 + (size_t)r * 128; gv = g2[r]; dst = w2 + (size_t)r * 128; }
    float2 v = *reinterpret_cast<const float2*>(src + lane * 2);
    float ss = v.x * v.x + v.y * v.y;
#pragma unroll
    for (int m = 1; m < 64; m <<= 1) ss += __shfl_xor(ss, m, 64);
    float sc = gv / sqrtf(ss);
    unsigned int packed = (unsigned int)f2h(v.x * sc) | ((unsigned int)f2h(v.y * sc) << 16);
    *reinterpret_cast<unsigned int*>(dst + lane * 2) = packed;
}

// ---------------- sigma_spe: sum of all pairwise distances ----------------
__global__ __launch_bounds__(256) void sigma_gemm(const u16* __restrict__ xh,
                                                  const float* __restrict__ sq,
                                                  float* __restrict__ accum) {
    __shared__ u16 xi[128][136];
    __shared__ u16 xj[128][136];
    int bid = blockIdx.x;
    int b = bid >> 10, rest = bid & 1023;
    int i0 = (rest >> 5) * 128, j0 = (rest & 31) * 128;
    int tid = threadIdx.x;
    const u16* xsrc = xh + (size_t)b * 4096 * 128;
    for (int t = tid; t < 2048; t += 256) {
        int row = t >> 4, c = (t & 15) * 8;
        *reinterpret_cast<uint4*>(&xi[row][c]) =
            *reinterpret_cast<const uint4*>(xsrc + (size_t)(i0 + row) * 128 + c);
    }
    for (int t = tid; t < 2048; t += 256) {
        int row = t >> 4, c = (t & 15) * 8;
        *reinterpret_cast<uint4*>(&xj[row][c]) =
            *reinterpret_cast<const uint4*>(xsrc + (size_t)(j0 + row) * 128 + c);
    }
    __syncthreads();
    int wave = tid >> 6, lane = tid & 63, lr = lane & 15, lg = lane >> 4;
    f16x8 ai[2][4];
#pragma unroll
    for (int m2 = 0; m2 < 2; ++m2)
#pragma unroll
        for (int ks = 0; ks < 4; ++ks)
            ai[m2][ks] = *reinterpret_cast<const f16x8*>(&xi[wave * 32 + m2 * 16 + lr][ks * 32 + lg * 8]);
    const float* sqb = sq + (size_t)b * 4096;
    float sqi[2][4];
#pragma unroll
    for (int m2 = 0; m2 < 2; ++m2)
#pragma unroll
        for (int r = 0; r < 4; ++r)
            sqi[m2][r] = sqb[i0 + wave * 32 + m2 * 16 + lg * 4 + r];
    float lsum = 0.f;
#pragma unroll
    for (int c = 0; c < 8; ++c) {
        f16x8 bj[4];
#pragma unroll
        for (int ks = 0; ks < 4; ++ks)
            bj[ks] = *reinterpret_cast<const f16x8*>(&xj[c * 16 + lr][ks * 32 + lg * 8]);
        float sqj = sqb[j0 + c * 16 + lr];
#pragma unroll
        for (int m2 = 0; m2 < 2; ++m2) {
            f32x4 acc = {0.f, 0.f, 0.f, 0.f};
#pragma unroll
            for (int ks = 0; ks < 4; ++ks)
                acc = __builtin_amdgcn_mfma_f32_16x16x32_f16(ai[m2][ks], bj[ks], acc, 0, 0, 0);
#pragma unroll
            for (int r = 0; r < 4; ++r) {
                float d2 = fmaf(-2.f, acc[r], sqi[m2][r] + sqj);
                lsum += sqrtf(fmaxf(d2, 0.f));
            }
        }
    }
#pragma unroll
    for (int m = 1; m < 64; m <<= 1) lsum += __shfl_xor(lsum, m, 64);
    if (lane == 0) atomicAdd(accum, lsum);
}

__global__ void sigma_fin(float* accum) {
    float sigma = accum[0] / 33554432.f;  // 2*4096*4096
    accum[1] = 1.f / (2.f * sigma * sigma);
}

// ---------------- qkv projection: [8192,128]@[128,384] -> q,k,vt (f16) ----------------
__global__ __launch_bounds__(256) void qkv_gemm(const u16* __restrict__ xh, const u16* __restrict__ wq,
                                                const float* __restrict__ bq,
                                                u16* __restrict__ q_ws, u16* __restrict__ k_ws,
                                                u16* __restrict__ vt_ws) {
    int cg = blockIdx.x & 1;
    int tok0 = (blockIdx.x >> 1) * 64 + (threadIdx.x >> 6) * 16;
    int lane = threadIdx.x & 63, lr = lane & 15, lg = lane >> 4;
    f16x8 a[4];
#pragma unroll
    for (int ks = 0; ks < 4; ++ks)
        a[ks] = *reinterpret_cast<const f16x8*>(xh + (size_t)(tok0 + lr) * 128 + ks * 32 + lg * 8);
#pragma unroll
    for (int ci = 0; ci < 12; ++ci) {
        int c = cg * 12 + ci;
        f32x4 acc = {0.f, 0.f, 0.f, 0.f};
#pragma unroll
        for (int ks = 0; ks < 4; ++ks) {
            f16x8 bw = *reinterpret_cast<const f16x8*>(wq + (size_t)(c * 16 + lr) * 128 + ks * 32 + lg * 8);
            acc = __builtin_amdgcn_mfma_f32_16x16x32_f16(a[ks], bw, acc, 0, 0, 0);
        }
        int j = c * 16 + lr;
        float bias = bq[j];
#pragma unroll
        for (int r = 0; r < 4; ++r) {
            int tokg = tok0 + lg * 4 + r;
            int b = tokg >> 12, n = tokg & 4095;
            u16 hv = f2h(acc[r] + bias);
            if (j < 128) {
                q_ws[((size_t)(b * 2 + (j >> 6)) * 4096 + n) * 64 + (j & 63)] = hv;
            } else if (j < 256) {
                int jj = j - 128;
                k_ws[((size_t)(b * 2 + (jj >> 6)) * 4096 + n) * 64 + (jj & 63)] = hv;
            } else {
                int jj = j - 256;
                vt_ws[((size_t)(b * 2 + (jj >> 6)) * 64 + (jj & 63)) * 4096 + n] = hv;
            }
        }
    }
}

// ---------------- fused masked attention (flash, key-split 2) ----------------
__global__ __launch_bounds__(512) void attn_fused(
    const u16* __restrict__ xh, const float* __restrict__ sq,
    const u16* __restrict__ q_ws, const u16* __restrict__ k_ws, const u16* __restrict__ vt_ws,
    const float* __restrict__ accum, float* __restrict__ opart, float2* __restrict__ ml,
    float c2) {
    __shared__ u16 k_lds[2][128][72];
    __shared__ u16 vt_lds[2][64][136];
    __shared__ u16 xk_lds[128][136];
    __shared__ u16 p_lds[8][16][136];
    __shared__ float sq_lds[128];

    const float c1 = accum[1];
    int idx = blockIdx.x;
    int split = idx & 1;
    int qt = (idx >> 1) & 63;
    int b = idx >> 7;
    int tid = threadIdx.x;
    int wave = tid >> 6, lane = tid & 63, lr = lane & 15, lg = lane >> 4;
    int h = wave >> 2, wq = wave & 3;
    int qrow_a = qt * 64 + wq * 16 + lr;      // A-frag row (token in batch)
    int qrow_c = qt * 64 + wq * 16 + lg * 4;  // C row base (+r)

    f16x8 aq[2], axq[4];
#pragma unroll
    for (int ks = 0; ks < 2; ++ks)
        aq[ks] = *reinterpret_cast<const f16x8*>(q_ws + ((size_t)(b * 2 + h) * 4096 + qrow_a) * 64 + ks * 32 + lg * 8);
#pragma unroll
    for (int ks = 0; ks < 4; ++ks)
        axq[ks] = *reinterpret_cast<const f16x8*>(xh + ((size_t)b * 4096 + qrow_a) * 128 + ks * 32 + lg * 8);

    float sqi[4], ixf[4], iyf[4];
#pragma unroll
    for (int r = 0; r < 4; ++r) {
        int i = qrow_c + r;
        sqi[r] = sq[(size_t)b * 4096 + i];
        ixf[r] = (float)(i >> 6);
        iyf[r] = (float)(i & 63);
    }

    f32x4 O[4];
    const f32x4 zero4 = {0.f, 0.f, 0.f, 0.f};
#pragma unroll
    for (int vd = 0; vd < 4; ++vd) O[vd] = zero4;
    float mrun[4], lrun[4];
#pragma unroll
    for (int r = 0; r < 4; ++r) { mrun[r] = -INFINITY; lrun[r] = 0.f; }

    for (int t = 0; t < 16; ++t) {
        int kb = (split * 16 + t) * 128;
        // ---- stage K, V^T, X_k, sq into LDS ----
        for (int u = tid; u < 2048; u += 512) {
            int h2 = u >> 10, id2 = u & 1023;
            int row = id2 >> 3, c8 = id2 & 7;
            *reinterpret_cast<uint4*>(&k_lds[h2][row][c8 * 8]) =
                *reinterpret_cast<const uint4*>(k_ws + ((size_t)(b * 2 + h2) * 4096 + kb + row) * 64 + c8 * 8);
        }
        for (int u = tid; u < 2048; u += 512) {
            int h2 = u >> 10, id2 = u & 1023;
            int row = id2 >> 4, c16 = id2 & 15;
            *reinterpret_cast<uint4*>(&vt_lds[h2][row][c16 * 8]) =
                *reinterpret_cast<const uint4*>(vt_ws + ((size_t)(b * 2 + h2) * 64 + row) * 4096 + kb + c16 * 8);
        }
        for (int u = tid; u < 2048; u += 512) {
            int row = u >> 4, c16 = u & 15;
            *reinterpret_cast<uint4*>(&xk_lds[row][c16 * 8]) =
                *reinterpret_cast<const uint4*>(xh + ((size_t)b * 4096 + kb + row) * 128 + c16 * 8);
        }
        if (tid < 128) sq_lds[tid] = sq[(size_t)b * 4096 + kb + tid];
        __syncthreads();

        float lt[8][4];
#pragma unroll
        for (int c = 0; c < 8; ++c) {
            f32x4 Dacc = zero4, Sacc = zero4;
#pragma unroll
            for (int ks = 0; ks < 4; ++ks) {
                f16x8 bx = *reinterpret_cast<const f16x8*>(&xk_lds[c * 16 + lr][ks * 32 + lg * 8]);
                Dacc = __builtin_amdgcn_mfma_f32_16x16x32_f16(axq[ks], bx, Dacc, 0, 0, 0);
            }
#pragma unroll
            for (int ks = 0; ks < 2; ++ks) {
                f16x8 bk = *reinterpret_cast<const f16x8*>(&k_lds[h][c * 16 + lr][ks * 32 + lg * 8]);
                Sacc = __builtin_amdgcn_mfma_f32_16x16x32_f16(aq[ks], bk, Sacc, 0, 0, 0);
            }
            int j = kb + c * 16 + lr;
            float sqj = sq_lds[c * 16 + lr];
            float jxf = (float)(j >> 6), jyf = (float)(j & 63);
#pragma unroll
            for (int r = 0; r < 4; ++r) {
                float d2 = fmaf(-2.f, Dacc[r], sqi[r] + sqj);
                float sd = sqrtf(fmaxf(d2, 0.f));
                float dx = ixf[r] - jxf, dy = iyf[r] - jyf;
                float spad = sqrtf(fmaf(dx, dx, dy * dy));
                float e = fmaf(sd, c1, spad * c2);
                float msk = exp2f(-e * LOG2E);
                lt[c][r] = Sacc[r] * 0.125f * msk;
            }
        }
        // ---- online softmax ----
        float sf[4];
#pragma unroll
        for (int r = 0; r < 4; ++r) {
            float mx = lt[0][r];
#pragma unroll
            for (int c = 1; c < 8; ++c) mx = fmaxf(mx, lt[c][r]);
#pragma unroll
            for (int m = 1; m < 16; m <<= 1) mx = fmaxf(mx, __shfl_xor(mx, m, 64));
            float mnew = fmaxf(mrun[r], mx);
            sf[r] = exp2f((mrun[r] - mnew) * LOG2E);
            float ps = 0.f;
#pragma unroll
            for (int c = 0; c < 8; ++c) {
                float p = exp2f((lt[c][r] - mnew) * LOG2E);
                lt[c][r] = p;
                ps += p;
            }
#pragma unroll
            for (int m = 1; m < 16; m <<= 1) ps += __shfl_xor(ps, m, 64);
            lrun[r] = lrun[r] * sf[r] + ps;
            mrun[r] = mnew;
        }
#pragma unroll
        for (int vd = 0; vd < 4; ++vd)
#pragma unroll
            for (int r = 0; r < 4; ++r) O[vd][r] *= sf[r];
        // ---- P -> LDS (wave-private region), then PV ----
#pragma unroll
        for (int c = 0; c < 8; ++c)
#pragma unroll
            for (int r = 0; r < 4; ++r)
                p_lds[wave][lg * 4 + r][c * 16 + lr] = f2h(lt[c][r]);
#pragma unroll
        for (int ks = 0; ks < 4; ++ks) {
            f16x8 pa = *reinterpret_cast<const f16x8*>(&p_lds[wave][lr][ks * 32 + lg * 8]);
#pragma unroll
            for (int vd = 0; vd < 4; ++vd) {
                f16x8 bv = *reinterpret_cast<const f16x8*>(&vt_lds[h][vd * 16 + lr][ks * 32 + lg * 8]);
                O[vd] = __builtin_amdgcn_mfma_f32_16x16x32_f16(pa, bv, O[vd], 0, 0, 0);
            }
        }
        __syncthreads();
    }
    // ---- epilogue: unnormalized partials + (m,l) ----
#pragma unroll
    for (int r = 0; r < 4; ++r) {
        int n = qrow_c + r;
        size_t obase = (((size_t)split * 2 + b) * 2 + h) * 4096 + n;
#pragma unroll
        for (int vd = 0; vd < 4; ++vd)
            opart[obase * 64 + vd * 16 + lr] = O[vd][r];
        if (lr == 0) ml[obase] = make_float2(mrun[r], lrun[r]);
    }
}

// ---------------- combine the 2 key-splits ----------------
__global__ __launch_bounds__(256) void combine(const float* __restrict__ opart,
                                               const float2* __restrict__ ml,
                                               u16* __restrict__ attn_h) {
    int e = blockIdx.x * 256 + threadIdx.x;  // < 1048576
    int tok = e >> 7, d = e & 127;
    int b = tok >> 12, n = tok & 4095;
    int h = d >> 6, dh = d & 63;
    size_t i0 = (((size_t)0 * 2 + b) * 2 + h) * 4096 + n;
    size_t i1 = (((size_t)1 * 2 + b) * 2 + h) * 4096 + n;
    float2 ml0 = ml[i0], ml1 = ml[i1];
    float M = fmaxf(ml0.x, ml1.x);
    float w0 = exp2f((ml0.x - M) * LOG2E);
    float w1 = exp2f((ml1.x - M) * LOG2E);
    float denom = w0 * ml0.y + w1 * ml1.y;
    float o0 = opart[i0 * 64 + dh], o1 = opart[i1 * 64 + dh];
    attn_h[(size_t)tok * 128 + d] = f2h((w0 * o0 + w1 * o1) / denom);
}

// ---------------- FF GEMMs: [8192,128]@[128,128] (+gelu) ----------------
__global__ __launch_bounds__(256) void ff_gemm(const u16* __restrict__ in, const u16* __restrict__ w,
                                               const float* __restrict__ bias, void* __restrict__ out,
                                               int act) {
    int cg = blockIdx.x & 1;
    int tok0 = (blockIdx.x >> 1) * 64 + (threadIdx.x >> 6) * 16;
    int lane = threadIdx.x & 63, lr = lane & 15, lg = lane >> 4;
    f16x8 a[4];
#pragma unroll
    for (int ks = 0; ks < 4; ++ks)
        a[ks] = *reinterpret_cast<const f16x8*>(in + (size_t)(tok0 + lr) * 128 + ks * 32 + lg * 8);
#pragma unroll
    for (int ci = 0; ci < 4; ++ci) {
        int c = cg * 4 + ci;
        f32x4 acc = {0.f, 0.f, 0.f, 0.f};
#pragma unroll
        for (int ks = 0; ks < 4; ++ks) {
            f16x8 bw = *reinterpret_cast<const f16x8*>(w + (size_t)(c * 16 + lr) * 128 + ks * 32 + lg * 8);
            acc = __builtin_amdgcn_mfma_f32_16x16x32_f16(a[ks], bw, acc, 0, 0, 0);
        }
        int j = c * 16 + lr;
        float bv = bias[j];
#pragma unroll
        for (int r = 0; r < 4; ++r) {
            int tok = tok0 + lg * 4 + r;
            float val = acc[r] + bv;
            if (act) {
                float g = 0.5f * val * (1.f + erff(val * 0.7071067811865475f));
                ((u16*)out)[(size_t)tok * 128 + j] = f2h(g);
            } else {
                ((float*)out)[(size_t)tok * 128 + j] = val;
            }
        }
    }
}

extern "C" void kernel_launch(void* const* d_in, const int* in_sizes, int n_in,
                              void* d_out, int out_size, void* d_ws, size_t ws_size,
                              hipStream_t stream) {
    const float* x     = (const float*)d_in[0];
    const float* v_qkv = (const float*)d_in[1];
    const float* g_qkv = (const float*)d_in[2];
    const float* b_qkv = (const float*)d_in[3];
    const float* v_ff1 = (const float*)d_in[4];
    const float* g_ff1 = (const float*)d_in[5];
    const float* b_ff1 = (const float*)d_in[6];
    const float* v_ff2 = (const float*)d_in[7];
    const float* g_ff2 = (const float*)d_in[8];
    const float* b_ff2 = (const float*)d_in[9];

    char* w = (char*)d_ws;
    size_t off = 0;
    float* accum = (float*)(w + off); off += 256;
    u16* xh      = (u16*)(w + off);   off += (size_t)8192 * 128 * 2;
    float* sqv   = (float*)(w + off); off += (size_t)8192 * 4;
    u16* wqkv    = (u16*)(w + off);   off += (size_t)384 * 128 * 2;
    u16* w1      = (u16*)(w + off);   off += (size_t)128 * 128 * 2;
    u16* w2      = (u16*)(w + off);   off += (size_t)128 * 128 * 2;
    u16* q_ws    = (u16*)(w + off);   off += (size_t)4 * 4096 * 64 * 2;
    u16* k_ws    = (u16*)(w + off);   off += (size_t)4 * 4096 * 64 * 2;
    u16* vt_ws   = (u16*)(w + off);   off += (size_t)4 * 4096 * 64 * 2;
    float* opart = (float*)(w + off); off += (size_t)8 * 4096 * 64 * 4;
    float2* mlv  = (float2*)(w + off); off += (size_t)8 * 4096 * 8;
    u16* attn_h  = (u16*)(w + off);   off += (size_t)8192 * 128 * 2;
    u16* h1      = (u16*)(w + off);   off += (size_t)8192 * 128 * 2;

    // sigma_spa: exact closed form over grid-delta histogram (deterministic)
    double ssum = 0.0;
    for (int dx = -63; dx <= 63; ++dx) {
        int adx = dx < 0 ? -dx : dx;
        for (int dy = -63; dy <= 63; ++dy) {
            int ady = dy < 0 ? -dy : dy;
            ssum += (double)(64 - adx) * (double)(64 - ady) * sqrt((double)(dx * dx + dy * dy));
        }
    }
    float sigma_spa = (float)(ssum / (4096.0 * 4096.0));
    float c2 = 1.0f / (2.0f * sigma_spa * sigma_spa);

    prep_x<<<2048, 256, 0, stream>>>(x, xh, sqv);
    prep_w<<<640, 64, 0, stream>>>(v_qkv, g_qkv, v_ff1, g_ff1, v_ff2, g_ff2, wqkv, w1, w2, accum);
    sigma_gemm<<<2048, 256, 0, stream>>>(xh, sqv, accum);
    sigma_fin<<<1, 1, 0, stream>>>(accum);
    qkv_gemm<<<256, 256, 0, stream>>>(xh, wqkv, b_qkv, q_ws, k_ws, vt_ws);
    attn_fused<<<256, 512, 0, stream>>>(xh, sqv, q_ws, k_ws, vt_ws, accum, opart, mlv, c2);
    combine<<<4096, 256, 0, stream>>>(opart, mlv, attn_h);
    ff_gemm<<<256, 256, 0, stream>>>(attn_h, w1, b_ff1, (void*)h1, 1);
    ff_gemm<<<256, 256, 0, stream>>>(h1, w2, b_ff2, d_out, 0);
}

// Round 3
// 235.427 us; speedup vs baseline: 1.7351x; 1.7351x over previous
//
#include <hip/hip_runtime.h>
#include <hip/hip_fp16.h>
#include <math.h>

typedef unsigned short u16;
typedef _Float16 f16x8 __attribute__((ext_vector_type(8)));
typedef float f32x4 __attribute__((ext_vector_type(4)));

#define LOG2E 1.4426950408889634f

static __device__ __forceinline__ u16 f2h(float f) {
    _Float16 h = (_Float16)f;
    return __builtin_bit_cast(u16, h);
}
static __device__ __forceinline__ float h2f(u16 u) {
    return (float)__builtin_bit_cast(_Float16, u);
}

// ---------------- prep: x -> f16, row sum-of-squares ----------------
__global__ __launch_bounds__(256) void prep_x(const float* __restrict__ x,
                                              u16* __restrict__ xh,
                                              float* __restrict__ sq) {
    int wave = threadIdx.x >> 6, lane = threadIdx.x & 63;
    int row = blockIdx.x * 4 + wave;             // 0..8191
    const float2 v = *reinterpret_cast<const float2*>(x + (size_t)row * 128 + lane * 2);
    float ss = v.x * v.x + v.y * v.y;
#pragma unroll
    for (int m = 1; m < 64; m <<= 1) ss += __shfl_xor(ss, m, 64);
    unsigned int packed = (unsigned int)f2h(v.x) | ((unsigned int)f2h(v.y) << 16);
    *reinterpret_cast<unsigned int*>(xh + (size_t)row * 128 + lane * 2) = packed;
    if (lane == 0) sq[row] = ss;
}

// ---------------- prep: weight-normed W -> f16 (row-major [out][128]) ----------------
__global__ __launch_bounds__(64) void prep_w(const float* __restrict__ vq, const float* __restrict__ gq,
                                             const float* __restrict__ v1, const float* __restrict__ g1,
                                             const float* __restrict__ v2, const float* __restrict__ g2,
                                             u16* __restrict__ wq, u16* __restrict__ w1, u16* __restrict__ w2) {
    int row = blockIdx.x, lane = threadIdx.x;
    const float* src; float gv; u16* dst; int r;
    if (row < 384)      { r = row;       src = vq + (size_t)r * 128; gv = gq[r]; dst = wq + (size_t)r * 128; }
    else if (row < 512) { r = row - 384; src = v1 + (size_t)r * 128; gv = g1[r]; dst = w1 + (size_t)r * 128; }
    else                { r = row - 512; src = v2 + (size_t)r * 128; gv = g2[r]; dst = w2 + (size_t)r * 128; }
    float2 v = *reinterpret_cast<const float2*>(src + lane * 2);
    float ss = v.x * v.x + v.y * v.y;
#pragma unroll
    for (int m = 1; m < 64; m <<= 1) ss += __shfl_xor(ss, m, 64);
    float sc = gv / sqrtf(ss);
    unsigned int packed = (unsigned int)f2h(v.x * sc) | ((unsigned int)f2h(v.y * sc) << 16);
    *reinterpret_cast<unsigned int*>(dst + lane * 2) = packed;
}

// ---------------- sigma_spe: sum of all pairwise distances -> per-block partials ----------------
__global__ __launch_bounds__(256) void sigma_gemm(const u16* __restrict__ xh,
                                                  const float* __restrict__ sq,
                                                  float* __restrict__ partial) {
    __shared__ u16 xi[128][136];
    __shared__ u16 xj[128][136];
    int bid = blockIdx.x;
    int b = bid >> 10, rest = bid & 1023;
    int i0 = (rest >> 5) * 128, j0 = (rest & 31) * 128;
    int tid = threadIdx.x;
    const u16* xsrc = xh + (size_t)b * 4096 * 128;
    for (int t = tid; t < 2048; t += 256) {
        int row = t >> 4, c = (t & 15) * 8;
        *reinterpret_cast<uint4*>(&xi[row][c]) =
            *reinterpret_cast<const uint4*>(xsrc + (size_t)(i0 + row) * 128 + c);
    }
    for (int t = tid; t < 2048; t += 256) {
        int row = t >> 4, c = (t & 15) * 8;
        *reinterpret_cast<uint4*>(&xj[row][c]) =
            *reinterpret_cast<const uint4*>(xsrc + (size_t)(j0 + row) * 128 + c);
    }
    __syncthreads();
    int wave = tid >> 6, lane = tid & 63, lr = lane & 15, lg = lane >> 4;
    f16x8 ai[2][4];
#pragma unroll
    for (int m2 = 0; m2 < 2; ++m2)
#pragma unroll
        for (int ks = 0; ks < 4; ++ks)
            ai[m2][ks] = *reinterpret_cast<const f16x8*>(&xi[wave * 32 + m2 * 16 + lr][ks * 32 + lg * 8]);
    const float* sqb = sq + (size_t)b * 4096;
    float sqi[2][4];
#pragma unroll
    for (int m2 = 0; m2 < 2; ++m2)
#pragma unroll
        for (int r = 0; r < 4; ++r)
            sqi[m2][r] = sqb[i0 + wave * 32 + m2 * 16 + lg * 4 + r];
    float lsum = 0.f;
#pragma unroll
    for (int c = 0; c < 8; ++c) {
        f16x8 bj[4];
#pragma unroll
        for (int ks = 0; ks < 4; ++ks)
            bj[ks] = *reinterpret_cast<const f16x8*>(&xj[c * 16 + lr][ks * 32 + lg * 8]);
        float sqj = sqb[j0 + c * 16 + lr];
#pragma unroll
        for (int m2 = 0; m2 < 2; ++m2) {
            f32x4 acc = {0.f, 0.f, 0.f, 0.f};
#pragma unroll
            for (int ks = 0; ks < 4; ++ks)
                acc = __builtin_amdgcn_mfma_f32_16x16x32_f16(ai[m2][ks], bj[ks], acc, 0, 0, 0);
#pragma unroll
            for (int r = 0; r < 4; ++r) {
                float d2 = fmaf(-2.f, acc[r], sqi[m2][r] + sqj);
                lsum += sqrtf(fmaxf(d2, 0.f));
            }
        }
    }
#pragma unroll
    for (int m = 1; m < 64; m <<= 1) lsum += __shfl_xor(lsum, m, 64);
    if (lane == 0) atomicAdd(&partial[bid], lsum);   // 4-way per block, distinct addresses
}

__global__ __launch_bounds__(256) void sigma_fin(const float* __restrict__ partial,
                                                 float* __restrict__ accum) {
    __shared__ float red[4];
    float s = 0.f;
    for (int i = threadIdx.x; i < 2048; i += 256) s += partial[i];
#pragma unroll
    for (int m = 1; m < 64; m <<= 1) s += __shfl_xor(s, m, 64);
    int w = threadIdx.x >> 6;
    if ((threadIdx.x & 63) == 0) red[w] = s;
    __syncthreads();
    if (threadIdx.x == 0) {
        float sigma = (red[0] + red[1] + red[2] + red[3]) / 33554432.f;  // 2*4096*4096
        accum[1] = LOG2E / (2.f * sigma * sigma);  // c1 * log2(e)
    }
}

// ---------------- qkv projection: q pre-scaled by 1/8 ----------------
__global__ __launch_bounds__(256) void qkv_gemm(const u16* __restrict__ xh, const u16* __restrict__ wq,
                                                const float* __restrict__ bq,
                                                u16* __restrict__ q_ws, u16* __restrict__ k_ws,
                                                u16* __restrict__ vt_ws) {
    int cg = blockIdx.x & 1;
    int tok0 = (blockIdx.x >> 1) * 64 + (threadIdx.x >> 6) * 16;
    int lane = threadIdx.x & 63, lr = lane & 15, lg = lane >> 4;
    f16x8 a[4];
#pragma unroll
    for (int ks = 0; ks < 4; ++ks)
        a[ks] = *reinterpret_cast<const f16x8*>(xh + (size_t)(tok0 + lr) * 128 + ks * 32 + lg * 8);
#pragma unroll
    for (int ci = 0; ci < 12; ++ci) {
        int c = cg * 12 + ci;
        f32x4 acc = {0.f, 0.f, 0.f, 0.f};
#pragma unroll
        for (int ks = 0; ks < 4; ++ks) {
            f16x8 bw = *reinterpret_cast<const f16x8*>(wq + (size_t)(c * 16 + lr) * 128 + ks * 32 + lg * 8);
            acc = __builtin_amdgcn_mfma_f32_16x16x32_f16(a[ks], bw, acc, 0, 0, 0);
        }
        int j = c * 16 + lr;
        float bias = bq[j];
        float sc = (j < 128) ? 0.125f : 1.0f;   // fold attention scale into q
#pragma unroll
        for (int r = 0; r < 4; ++r) {
            int tokg = tok0 + lg * 4 + r;
            int b = tokg >> 12, n = tokg & 4095;
            u16 hv = f2h((acc[r] + bias) * sc);
            if (j < 128) {
                q_ws[((size_t)(b * 2 + (j >> 6)) * 4096 + n) * 64 + (j & 63)] = hv;
            } else if (j < 256) {
                int jj = j - 128;
                k_ws[((size_t)(b * 2 + (jj >> 6)) * 4096 + n) * 64 + (jj & 63)] = hv;
            } else {
                int jj = j - 256;
                vt_ws[((size_t)(b * 2 + (jj >> 6)) * 64 + (jj & 63)) * 4096 + n] = hv;
            }
        }
    }
}

// ---------------- fused masked attention: fixed-max softmax, both heads per wave ----------------
__global__ __launch_bounds__(256, 2) void attn_fused(
    const u16* __restrict__ xh, const float* __restrict__ sq,
    const u16* __restrict__ q_ws, const u16* __restrict__ k_ws, const u16* __restrict__ vt_ws,
    const float* __restrict__ accum, u16* __restrict__ opart, float* __restrict__ l_ws,
    float c2L) {
    __shared__ u16 k_lds[2][64][72];
    __shared__ u16 vt_lds[2][64][72];
    __shared__ u16 xk_lds[64][136];
    __shared__ u16 p_lds[4][2][16][72];
    __shared__ float sq_lds[64];

    const float c1L = accum[1];
    const float NEG8L = -8.0f * LOG2E;
    int idx = blockIdx.x;
    int qt = idx & 63, split = (idx >> 6) & 3, b = idx >> 8;  // 512 blocks
    int tid = threadIdx.x;
    int w = tid >> 6, lane = tid & 63, lr = lane & 15, lg = lane >> 4;
    int q0 = qt * 64 + w * 16;

    f16x8 aq[2][2], axq[4];
#pragma unroll
    for (int h = 0; h < 2; ++h)
#pragma unroll
        for (int ks = 0; ks < 2; ++ks)
            aq[h][ks] = *reinterpret_cast<const f16x8*>(
                q_ws + ((size_t)(b * 2 + h) * 4096 + q0 + lr) * 64 + ks * 32 + lg * 8);
#pragma unroll
    for (int ks = 0; ks < 4; ++ks)
        axq[ks] = *reinterpret_cast<const f16x8*>(
            xh + ((size_t)b * 4096 + q0 + lr) * 128 + ks * 32 + lg * 8);

    float sqi[4], ixf[4], iyf[4];
#pragma unroll
    for (int r = 0; r < 4; ++r) {
        int i = q0 + lg * 4 + r;
        sqi[r] = sq[(size_t)b * 4096 + i];
        ixf[r] = (float)(i >> 6);
        iyf[r] = (float)(i & 63);
    }

    const f32x4 zero4 = {0.f, 0.f, 0.f, 0.f};
    f32x4 O[2][4];
    float lsum[2][4];
#pragma unroll
    for (int h = 0; h < 2; ++h)
#pragma unroll
        for (int vd = 0; vd < 4; ++vd) O[h][vd] = zero4;
#pragma unroll
    for (int h = 0; h < 2; ++h)
#pragma unroll
        for (int r = 0; r < 4; ++r) lsum[h][r] = 0.f;

    for (int t = 0; t < 16; ++t) {
        int kb = split * 1024 + t * 64;
        // ---- stage K (both heads), V^T (both heads), X_k, sq ----
#pragma unroll
        for (int it = 0; it < 4; ++it) {
            int i2 = tid + it * 256;                 // [0,1024)
            int h2 = i2 >> 9, rem = i2 & 511;
            int row = rem >> 3, c8 = rem & 7;
            *reinterpret_cast<uint4*>(&k_lds[h2][row][c8 * 8]) =
                *reinterpret_cast<const uint4*>(k_ws + ((size_t)(b * 2 + h2) * 4096 + kb + row) * 64 + c8 * 8);
        }
#pragma unroll
        for (int it = 0; it < 4; ++it) {
            int i2 = tid + it * 256;
            int h2 = i2 >> 9, rem = i2 & 511;
            int row = rem >> 3, c8 = rem & 7;       // row = dh
            *reinterpret_cast<uint4*>(&vt_lds[h2][row][c8 * 8]) =
                *reinterpret_cast<const uint4*>(vt_ws + ((size_t)(b * 2 + h2) * 64 + row) * 4096 + kb + c8 * 8);
        }
#pragma unroll
        for (int it = 0; it < 4; ++it) {
            int i2 = tid + it * 256;
            int row = i2 >> 4, c16 = i2 & 15;
            *reinterpret_cast<uint4*>(&xk_lds[row][c16 * 8]) =
                *reinterpret_cast<const uint4*>(xh + ((size_t)b * 4096 + kb + row) * 128 + c16 * 8);
        }
        if (tid < 64) sq_lds[tid] = sq[(size_t)b * 4096 + kb + tid];
        __syncthreads();

#pragma unroll
        for (int c = 0; c < 4; ++c) {
            f32x4 Dacc = zero4, S0 = zero4, S1 = zero4;
#pragma unroll
            for (int ks = 0; ks < 4; ++ks) {
                f16x8 bx = *reinterpret_cast<const f16x8*>(&xk_lds[c * 16 + lr][ks * 32 + lg * 8]);
                Dacc = __builtin_amdgcn_mfma_f32_16x16x32_f16(axq[ks], bx, Dacc, 0, 0, 0);
            }
#pragma unroll
            for (int ks = 0; ks < 2; ++ks) {
                f16x8 bk0 = *reinterpret_cast<const f16x8*>(&k_lds[0][c * 16 + lr][ks * 32 + lg * 8]);
                S0 = __builtin_amdgcn_mfma_f32_16x16x32_f16(aq[0][ks], bk0, S0, 0, 0, 0);
                f16x8 bk1 = *reinterpret_cast<const f16x8*>(&k_lds[1][c * 16 + lr][ks * 32 + lg * 8]);
                S1 = __builtin_amdgcn_mfma_f32_16x16x32_f16(aq[1][ks], bk1, S1, 0, 0, 0);
            }
            int j = kb + c * 16 + lr;
            float sqj = sq_lds[c * 16 + lr];
            float jxf = (float)(j >> 6), jyf = (float)(j & 63);
#pragma unroll
            for (int r = 0; r < 4; ++r) {
                float d2 = fmaf(-2.f, Dacc[r], sqi[r] + sqj);
                float sd = sqrtf(fmaxf(d2, 0.f));
                float dx = ixf[r] - jxf, dy = iyf[r] - jyf;
                float spad = sqrtf(fmaf(dx, dx, dy * dy));
                float tt = fmaf(sd, c1L, spad * c2L);
                float msk = exp2f(-tt);
                float p0 = exp2f(fmaf(S0[r] * msk, LOG2E, NEG8L));
                float p1 = exp2f(fmaf(S1[r] * msk, LOG2E, NEG8L));
                p0 = fminf(p0, 60000.f);
                p1 = fminf(p1, 60000.f);
                lsum[0][r] += p0;
                lsum[1][r] += p1;
                p_lds[w][0][lg * 4 + r][c * 16 + lr] = f2h(p0);
                p_lds[w][1][lg * 4 + r][c * 16 + lr] = f2h(p1);
            }
        }
        // ---- PV (P writes/reads are wave-private; compiler inserts lgkmcnt) ----
#pragma unroll
        for (int h = 0; h < 2; ++h)
#pragma unroll
            for (int ks = 0; ks < 2; ++ks) {
                f16x8 pa = *reinterpret_cast<const f16x8*>(&p_lds[w][h][lr][ks * 32 + lg * 8]);
#pragma unroll
                for (int vd = 0; vd < 4; ++vd) {
                    f16x8 bv = *reinterpret_cast<const f16x8*>(&vt_lds[h][vd * 16 + lr][ks * 32 + lg * 8]);
                    O[h][vd] = __builtin_amdgcn_mfma_f32_16x16x32_f16(pa, bv, O[h][vd], 0, 0, 0);
                }
            }
        __syncthreads();
    }
    // ---- epilogue: unnormalized O (f16) + row-sums l ----
#pragma unroll
    for (int r = 0; r < 4; ++r) {
        int q = q0 + lg * 4 + r;
#pragma unroll
        for (int h = 0; h < 2; ++h) {
            float ls = lsum[h][r];
#pragma unroll
            for (int m = 1; m < 16; m <<= 1) ls += __shfl_xor(ls, m, 64);
            size_t base = (((size_t)split * 2 + b) * 2 + h) * 4096 + q;
            if (lr == 0) l_ws[base] = ls;
#pragma unroll
            for (int vd = 0; vd < 4; ++vd)
                opart[base * 64 + vd * 16 + lr] = f2h(O[h][vd][r]);
        }
    }
}

// ---------------- combine the 4 key-splits: plain sum + divide ----------------
__global__ __launch_bounds__(256) void combine(const u16* __restrict__ opart,
                                               const float* __restrict__ l_ws,
                                               u16* __restrict__ attn_h) {
    int e = blockIdx.x * 256 + threadIdx.x;  // < 1048576
    int tok = e >> 7, d = e & 127;
    int b = tok >> 12, n = tok & 4095;
    int h = d >> 6, dh = d & 63;
    float O = 0.f, L = 0.f;
#pragma unroll
    for (int s = 0; s < 4; ++s) {
        size_t base = (((size_t)s * 2 + b) * 2 + h) * 4096 + n;
        O += h2f(opart[base * 64 + dh]);
        L += l_ws[base];
    }
    attn_h[(size_t)tok * 128 + d] = f2h(O / L);
}

// ---------------- FF GEMMs: [8192,128]@[128,128] (+gelu) ----------------
__global__ __launch_bounds__(256) void ff_gemm(const u16* __restrict__ in, const u16* __restrict__ w,
                                               const float* __restrict__ bias, void* __restrict__ out,
                                               int act) {
    int cg = blockIdx.x & 1;
    int tok0 = (blockIdx.x >> 1) * 64 + (threadIdx.x >> 6) * 16;
    int lane = threadIdx.x & 63, lr = lane & 15, lg = lane >> 4;
    f16x8 a[4];
#pragma unroll
    for (int ks = 0; ks < 4; ++ks)
        a[ks] = *reinterpret_cast<const f16x8*>(in + (size_t)(tok0 + lr) * 128 + ks * 32 + lg * 8);
#pragma unroll
    for (int ci = 0; ci < 4; ++ci) {
        int c = cg * 4 + ci;
        f32x4 acc = {0.f, 0.f, 0.f, 0.f};
#pragma unroll
        for (int ks = 0; ks < 4; ++ks) {
            f16x8 bw = *reinterpret_cast<const f16x8*>(w + (size_t)(c * 16 + lr) * 128 + ks * 32 + lg * 8);
            acc = __builtin_amdgcn_mfma_f32_16x16x32_f16(a[ks], bw, acc, 0, 0, 0);
        }
        int j = c * 16 + lr;
        float bv = bias[j];
#pragma unroll
        for (int r = 0; r < 4; ++r) {
            int tok = tok0 + lg * 4 + r;
            float val = acc[r] + bv;
            if (act) {
                float g = 0.5f * val * (1.f + erff(val * 0.7071067811865475f));
                ((u16*)out)[(size_t)tok * 128 + j] = f2h(g);
            } else {
                ((float*)out)[(size_t)tok * 128 + j] = val;
            }
        }
    }
}

extern "C" void kernel_launch(void* const* d_in, const int* in_sizes, int n_in,
                              void* d_out, int out_size, void* d_ws, size_t ws_size,
                              hipStream_t stream) {
    const float* x     = (const float*)d_in[0];
    const float* v_qkv = (const float*)d_in[1];
    const float* g_qkv = (const float*)d_in[2];
    const float* b_qkv = (const float*)d_in[3];
    const float* v_ff1 = (const float*)d_in[4];
    const float* g_ff1 = (const float*)d_in[5];
    const float* b_ff1 = (const float*)d_in[6];
    const float* v_ff2 = (const float*)d_in[7];
    const float* g_ff2 = (const float*)d_in[8];
    const float* b_ff2 = (const float*)d_in[9];

    char* w = (char*)d_ws;
    size_t off = 0;
    float* accum   = (float*)(w + off); off += 256;
    float* partial = (float*)(w + off); off += 2048 * 4;
    u16* xh      = (u16*)(w + off);   off += (size_t)8192 * 128 * 2;
    float* sqv   = (float*)(w + off); off += (size_t)8192 * 4;
    u16* wqkv    = (u16*)(w + off);   off += (size_t)384 * 128 * 2;
    u16* w1      = (u16*)(w + off);   off += (size_t)128 * 128 * 2;
    u16* w2      = (u16*)(w + off);   off += (size_t)128 * 128 * 2;
    u16* q_ws    = (u16*)(w + off);   off += (size_t)4 * 4096 * 64 * 2;
    u16* k_ws    = (u16*)(w + off);   off += (size_t)4 * 4096 * 64 * 2;
    u16* vt_ws   = (u16*)(w + off);   off += (size_t)4 * 4096 * 64 * 2;
    u16* opart   = (u16*)(w + off);   off += (size_t)16 * 4096 * 64 * 2;   // [split4][b2][h2][n][64] f16
    float* l_ws  = (float*)(w + off); off += (size_t)16 * 4096 * 4;        // [split4][b2][h2][n]
    u16* attn_h  = (u16*)(w + off);   off += (size_t)8192 * 128 * 2;
    u16* h1      = (u16*)(w + off);   off += (size_t)8192 * 128 * 2;

    // sigma_spa: exact closed form over grid-delta histogram (deterministic)
    double ssum = 0.0;
    for (int dx = -63; dx <= 63; ++dx) {
        int adx = dx < 0 ? -dx : dx;
        for (int dy = -63; dy <= 63; ++dy) {
            int ady = dy < 0 ? -dy : dy;
            ssum += (double)(64 - adx) * (double)(64 - ady) * sqrt((double)(dx * dx + dy * dy));
        }
    }
    float sigma_spa = (float)(ssum / (4096.0 * 4096.0));
    float c2L = LOG2E / (2.0f * sigma_spa * sigma_spa);

    hipMemsetAsync(w, 0, 256 + 2048 * 4, stream);   // accum + sigma partials

    prep_x<<<2048, 256, 0, stream>>>(x, xh, sqv);
    prep_w<<<640, 64, 0, stream>>>(v_qkv, g_qkv, v_ff1, g_ff1, v_ff2, g_ff2, wqkv, w1, w2);
    sigma_gemm<<<2048, 256, 0, stream>>>(xh, sqv, partial);
    sigma_fin<<<1, 256, 0, stream>>>(partial, accum);
    qkv_gemm<<<256, 256, 0, stream>>>(xh, wqkv, b_qkv, q_ws, k_ws, vt_ws);
    attn_fused<<<512, 256, 0, stream>>>(xh, sqv, q_ws, k_ws, vt_ws, accum, opart, l_ws, c2L);
    combine<<<4096, 256, 0, stream>>>(opart, l_ws, attn_h);
    ff_gemm<<<256, 256, 0, stream>>>(attn_h, w1, b_ff1, (void*)h1, 1);
    ff_gemm<<<256, 256, 0, stream>>>(h1, w2, b_ff2, d_out, 0);
}

// Round 4
// 212.249 us; speedup vs baseline: 1.9246x; 1.1092x over previous
//
#include <hip/hip_runtime.h>
#include <hip/hip_fp16.h>
#include <math.h>

typedef unsigned short u16;
typedef _Float16 f16x8 __attribute__((ext_vector_type(8)));
typedef float f32x4 __attribute__((ext_vector_type(4)));

#define LOG2E 1.4426950408889634f

static __device__ __forceinline__ u16 f2h(float f) {
    _Float16 h = (_Float16)f;
    return __builtin_bit_cast(u16, h);
}
static __device__ __forceinline__ float h2f(u16 u) {
    return (float)__builtin_bit_cast(_Float16, u);
}
// raw v_sqrt_f32 / v_exp_f32 (~1ULP) — avoids IEEE sqrt expansion (~14 instrs)
static __device__ __forceinline__ float fsqrt_raw(float x) {
    float r; asm("v_sqrt_f32 %0, %1" : "=v"(r) : "v"(x)); return r;
}
static __device__ __forceinline__ float fexp2_raw(float x) {
    float r; asm("v_exp_f32 %0, %1" : "=v"(r) : "v"(x)); return r;
}

// ---------------- prep: x -> f16, row sum-of-squares ----------------
__global__ __launch_bounds__(256) void prep_x(const float* __restrict__ x,
                                              u16* __restrict__ xh,
                                              float* __restrict__ sq) {
    int wave = threadIdx.x >> 6, lane = threadIdx.x & 63;
    int row = blockIdx.x * 4 + wave;             // 0..8191
    const float2 v = *reinterpret_cast<const float2*>(x + (size_t)row * 128 + lane * 2);
    float ss = v.x * v.x + v.y * v.y;
#pragma unroll
    for (int m = 1; m < 64; m <<= 1) ss += __shfl_xor(ss, m, 64);
    unsigned int packed = (unsigned int)f2h(v.x) | ((unsigned int)f2h(v.y) << 16);
    *reinterpret_cast<unsigned int*>(xh + (size_t)row * 128 + lane * 2) = packed;
    if (lane == 0) sq[row] = ss;
}

// ---------------- prep: weight-normed W -> f16 (row-major [out][128]) ----------------
__global__ __launch_bounds__(64) void prep_w(const float* __restrict__ vq, const float* __restrict__ gq,
                                             const float* __restrict__ v1, const float* __restrict__ g1,
                                             const float* __restrict__ v2, const float* __restrict__ g2,
                                             u16* __restrict__ wq, u16* __restrict__ w1, u16* __restrict__ w2) {
    int row = blockIdx.x, lane = threadIdx.x;
    const float* src; float gv; u16* dst; int r;
    if (row < 384)      { r = row;       src = vq + (size_t)r * 128; gv = gq[r]; dst = wq + (size_t)r * 128; }
    else if (row < 512) { r = row - 384; src = v1 + (size_t)r * 128; gv = g1[r]; dst = w1 + (size_t)r * 128; }
    else                { r = row - 512; src = v2 + (size_t)r * 128; gv = g2[r]; dst = w2 + (size_t)r * 128; }
    float2 v = *reinterpret_cast<const float2*>(src + lane * 2);
    float ss = v.x * v.x + v.y * v.y;
#pragma unroll
    for (int m = 1; m < 64; m <<= 1) ss += __shfl_xor(ss, m, 64);
    float sc = gv / sqrtf(ss);
    unsigned int packed = (unsigned int)f2h(v.x * sc) | ((unsigned int)f2h(v.y * sc) << 16);
    *reinterpret_cast<unsigned int*>(dst + lane * 2) = packed;
}

// ---------------- spatial mask table: tab[dx+63][iy][jy] = LOG2E*exp(-dist*c2) ----------------
__global__ __launch_bounds__(256) void spa_tab_k(float* __restrict__ tab, float c2) {
    int id = blockIdx.x * 256 + threadIdx.x;        // < 127*4096
    int dxi = id >> 12, rem = id & 4095;
    int iy = rem >> 6, jy = rem & 63;
    float dx = (float)(dxi - 63), dy = (float)(iy - jy);
    float d = fsqrt_raw(fmaf(dx, dx, dy * dy));
    tab[id] = LOG2E * fexp2_raw(-d * c2 * LOG2E);
}

// ---------------- sigma_spe: sum of all pairwise distances -> per-block partials ----------------
__global__ __launch_bounds__(256) void sigma_gemm(const u16* __restrict__ xh,
                                                  const float* __restrict__ sq,
                                                  float* __restrict__ partial) {
    __shared__ u16 xi[128][136];
    __shared__ u16 xj[128][136];
    int bid = blockIdx.x;
    int b = bid >> 10, rest = bid & 1023;
    int i0 = (rest >> 5) * 128, j0 = (rest & 31) * 128;
    int tid = threadIdx.x;
    const u16* xsrc = xh + (size_t)b * 4096 * 128;
    for (int t = tid; t < 2048; t += 256) {
        int row = t >> 4, c = (t & 15) * 8;
        *reinterpret_cast<uint4*>(&xi[row][c]) =
            *reinterpret_cast<const uint4*>(xsrc + (size_t)(i0 + row) * 128 + c);
    }
    for (int t = tid; t < 2048; t += 256) {
        int row = t >> 4, c = (t & 15) * 8;
        *reinterpret_cast<uint4*>(&xj[row][c]) =
            *reinterpret_cast<const uint4*>(xsrc + (size_t)(j0 + row) * 128 + c);
    }
    __syncthreads();
    int wave = tid >> 6, lane = tid & 63, lr = lane & 15, lg = lane >> 4;
    f16x8 ai[2][4];
#pragma unroll
    for (int m2 = 0; m2 < 2; ++m2)
#pragma unroll
        for (int ks = 0; ks < 4; ++ks)
            ai[m2][ks] = *reinterpret_cast<const f16x8*>(&xi[wave * 32 + m2 * 16 + lr][ks * 32 + lg * 8]);
    const float* sqb = sq + (size_t)b * 4096;
    float sqi[2][4];
#pragma unroll
    for (int m2 = 0; m2 < 2; ++m2)
#pragma unroll
        for (int r = 0; r < 4; ++r)
            sqi[m2][r] = sqb[i0 + wave * 32 + m2 * 16 + lg * 4 + r];
    float lsum = 0.f;
#pragma unroll
    for (int c = 0; c < 8; ++c) {
        f16x8 bj[4];
#pragma unroll
        for (int ks = 0; ks < 4; ++ks)
            bj[ks] = *reinterpret_cast<const f16x8*>(&xj[c * 16 + lr][ks * 32 + lg * 8]);
        float sqj = sqb[j0 + c * 16 + lr];
#pragma unroll
        for (int m2 = 0; m2 < 2; ++m2) {
            f32x4 acc = {0.f, 0.f, 0.f, 0.f};
#pragma unroll
            for (int ks = 0; ks < 4; ++ks)
                acc = __builtin_amdgcn_mfma_f32_16x16x32_f16(ai[m2][ks], bj[ks], acc, 0, 0, 0);
#pragma unroll
            for (int r = 0; r < 4; ++r) {
                float d2 = fmaf(-2.f, acc[r], sqi[m2][r] + sqj);
                lsum += fsqrt_raw(fmaxf(d2, 0.f));
            }
        }
    }
#pragma unroll
    for (int m = 1; m < 64; m <<= 1) lsum += __shfl_xor(lsum, m, 64);
    if (lane == 0) atomicAdd(&partial[bid], lsum);
}

__global__ __launch_bounds__(256) void sigma_fin(const float* __restrict__ partial,
                                                 float* __restrict__ accum) {
    __shared__ float red[4];
    float s = 0.f;
    for (int i = threadIdx.x; i < 2048; i += 256) s += partial[i];
#pragma unroll
    for (int m = 1; m < 64; m <<= 1) s += __shfl_xor(s, m, 64);
    int w = threadIdx.x >> 6;
    if ((threadIdx.x & 63) == 0) red[w] = s;
    __syncthreads();
    if (threadIdx.x == 0) {
        float sigma = (red[0] + red[1] + red[2] + red[3]) / 33554432.f;  // 2*4096*4096
        accum[1] = -LOG2E / (2.f * sigma * sigma);  // -c1 * log2(e)
    }
}

// ---------------- qkv projection: q pre-scaled by 1/8 ----------------
__global__ __launch_bounds__(256) void qkv_gemm(const u16* __restrict__ xh, const u16* __restrict__ wq,
                                                const float* __restrict__ bq,
                                                u16* __restrict__ q_ws, u16* __restrict__ k_ws,
                                                u16* __restrict__ vt_ws) {
    int cg = blockIdx.x & 1;
    int tok0 = (blockIdx.x >> 1) * 64 + (threadIdx.x >> 6) * 16;
    int lane = threadIdx.x & 63, lr = lane & 15, lg = lane >> 4;
    f16x8 a[4];
#pragma unroll
    for (int ks = 0; ks < 4; ++ks)
        a[ks] = *reinterpret_cast<const f16x8*>(xh + (size_t)(tok0 + lr) * 128 + ks * 32 + lg * 8);
#pragma unroll
    for (int ci = 0; ci < 12; ++ci) {
        int c = cg * 12 + ci;
        f32x4 acc = {0.f, 0.f, 0.f, 0.f};
#pragma unroll
        for (int ks = 0; ks < 4; ++ks) {
            f16x8 bw = *reinterpret_cast<const f16x8*>(wq + (size_t)(c * 16 + lr) * 128 + ks * 32 + lg * 8);
            acc = __builtin_amdgcn_mfma_f32_16x16x32_f16(a[ks], bw, acc, 0, 0, 0);
        }
        int j = c * 16 + lr;
        float bias = bq[j];
        float sc = (j < 128) ? 0.125f : 1.0f;   // fold attention scale into q
#pragma unroll
        for (int r = 0; r < 4; ++r) {
            int tokg = tok0 + lg * 4 + r;
            int b = tokg >> 12, n = tokg & 4095;
            u16 hv = f2h((acc[r] + bias) * sc);
            if (j < 128) {
                q_ws[((size_t)(b * 2 + (j >> 6)) * 4096 + n) * 64 + (j & 63)] = hv;
            } else if (j < 256) {
                int jj = j - 128;
                k_ws[((size_t)(b * 2 + (jj >> 6)) * 4096 + n) * 64 + (jj & 63)] = hv;
            } else {
                int jj = j - 256;
                vt_ws[((size_t)(b * 2 + (jj >> 6)) * 64 + (jj & 63)) * 4096 + n] = hv;
            }
        }
    }
}

// ---------------- fused masked attention: 32-key tiles, split 8, table mask ----------------
__global__ __launch_bounds__(256, 4) void attn_fused(
    const u16* __restrict__ xh, const float* __restrict__ sq,
    const u16* __restrict__ q_ws, const u16* __restrict__ k_ws, const u16* __restrict__ vt_ws,
    const float* __restrict__ accum, const float* __restrict__ spa,
    u16* __restrict__ opart, float* __restrict__ l_ws) {
    __shared__ u16 k_lds[2][32][72];     // 9216 B
    __shared__ u16 vt_lds[2][64][40];    // 10240 B
    __shared__ u16 xk_lds[32][136];      // 8704 B
    __shared__ u16 p_lds[4][2][16][40];  // 10240 B
    __shared__ float sq_lds[32];         // 128 B   (total 38528 B -> 4 blocks/CU)

    const float nc1L = accum[1];                 // -c1*LOG2E
    const float NEG8L = -8.0f * LOG2E;
    int idx = blockIdx.x;                        // 1024 blocks
    int qt = idx & 63, split = (idx >> 6) & 7, b = idx >> 9;
    int tid = threadIdx.x;
    int w = tid >> 6, lane = tid & 63, lr = lane & 15, lg = lane >> 4;
    int q0 = qt * 64 + w * 16;

    f16x8 aq[2][2], axq[4];
#pragma unroll
    for (int h = 0; h < 2; ++h)
#pragma unroll
        for (int ks = 0; ks < 2; ++ks)
            aq[h][ks] = *reinterpret_cast<const f16x8*>(
                q_ws + ((size_t)(b * 2 + h) * 4096 + q0 + lr) * 64 + ks * 32 + lg * 8);
#pragma unroll
    for (int ks = 0; ks < 4; ++ks)
        axq[ks] = *reinterpret_cast<const f16x8*>(
            xh + ((size_t)b * 4096 + q0 + lr) * 128 + ks * 32 + lg * 8);

    float sqi[4];
    int rowoff[4];                               // spa row offset per r (iy = w*16+lg*4+r)
#pragma unroll
    for (int r = 0; r < 4; ++r) {
        sqi[r] = sq[(size_t)b * 4096 + q0 + lg * 4 + r];
        rowoff[r] = (w * 16 + lg * 4 + r) * 64 + lr;
    }

    const f32x4 zero4 = {0.f, 0.f, 0.f, 0.f};
    f32x4 O[2][4];
    float lsum[2][4];
#pragma unroll
    for (int h = 0; h < 2; ++h)
#pragma unroll
        for (int vd = 0; vd < 4; ++vd) O[h][vd] = zero4;
#pragma unroll
    for (int h = 0; h < 2; ++h)
#pragma unroll
        for (int r = 0; r < 4; ++r) lsum[h][r] = 0.f;

    for (int t = 0; t < 16; ++t) {
        int kb = split * 512 + t * 32;
        int dxi = qt - (kb >> 6) + 63;
        const float* spa_t = spa + (size_t)dxi * 4096 + (kb & 63);
        // ---- stage K (both heads), V^T (both heads), X_k, sq ----
#pragma unroll
        for (int it = 0; it < 2; ++it) {
            int i2 = tid + it * 256;             // [0,512)
            int h2 = i2 >> 8, rem = i2 & 255;
            int row = rem >> 3, c8 = rem & 7;    // row=key, 64 dh = 8 uint4
            *reinterpret_cast<uint4*>(&k_lds[h2][row][c8 * 8]) =
                *reinterpret_cast<const uint4*>(k_ws + ((size_t)(b * 2 + h2) * 4096 + kb + row) * 64 + c8 * 8);
        }
#pragma unroll
        for (int it = 0; it < 2; ++it) {
            int i2 = tid + it * 256;
            int h2 = i2 >> 8, rem = i2 & 255;
            int row = rem >> 2, c4 = rem & 3;    // row=dh, 32 keys = 4 uint4
            *reinterpret_cast<uint4*>(&vt_lds[h2][row][c4 * 8]) =
                *reinterpret_cast<const uint4*>(vt_ws + ((size_t)(b * 2 + h2) * 64 + row) * 4096 + kb + c4 * 8);
        }
#pragma unroll
        for (int it = 0; it < 2; ++it) {
            int i2 = tid + it * 256;
            int row = i2 >> 4, c16 = i2 & 15;    // row=key, 128 = 16 uint4
            *reinterpret_cast<uint4*>(&xk_lds[row][c16 * 8]) =
                *reinterpret_cast<const uint4*>(xh + ((size_t)b * 4096 + kb + row) * 128 + c16 * 8);
        }
        if (tid < 32) sq_lds[tid] = sq[(size_t)b * 4096 + kb + tid];
        __syncthreads();

#pragma unroll
        for (int c = 0; c < 2; ++c) {
            f32x4 Dacc = zero4, S0 = zero4, S1 = zero4;
#pragma unroll
            for (int ks = 0; ks < 4; ++ks) {
                f16x8 bx = *reinterpret_cast<const f16x8*>(&xk_lds[c * 16 + lr][ks * 32 + lg * 8]);
                Dacc = __builtin_amdgcn_mfma_f32_16x16x32_f16(axq[ks], bx, Dacc, 0, 0, 0);
            }
#pragma unroll
            for (int ks = 0; ks < 2; ++ks) {
                f16x8 bk0 = *reinterpret_cast<const f16x8*>(&k_lds[0][c * 16 + lr][ks * 32 + lg * 8]);
                S0 = __builtin_amdgcn_mfma_f32_16x16x32_f16(aq[0][ks], bk0, S0, 0, 0, 0);
                f16x8 bk1 = *reinterpret_cast<const f16x8*>(&k_lds[1][c * 16 + lr][ks * 32 + lg * 8]);
                S1 = __builtin_amdgcn_mfma_f32_16x16x32_f16(aq[1][ks], bk1, S1, 0, 0, 0);
            }
            float sqj = sq_lds[c * 16 + lr];
            float sp[4];
#pragma unroll
            for (int r = 0; r < 4; ++r) sp[r] = spa_t[rowoff[r] + c * 16];
#pragma unroll
            for (int r = 0; r < 4; ++r) {
                float d2 = fmaf(-2.f, Dacc[r], sqi[r] + sqj);
                float sd = fsqrt_raw(fmaxf(d2, 0.f));
                float spe = fexp2_raw(sd * nc1L);
                float mskL = sp[r] * spe;        // table already carries LOG2E
                float p0 = fexp2_raw(fmaf(S0[r], mskL, NEG8L));
                float p1 = fexp2_raw(fmaf(S1[r], mskL, NEG8L));
                lsum[0][r] += p0;
                lsum[1][r] += p1;
                p_lds[w][0][lg * 4 + r][c * 16 + lr] = f2h(p0);
                p_lds[w][1][lg * 4 + r][c * 16 + lr] = f2h(p1);
            }
        }
        // ---- PV: K=32, single MFMA per (h,vd) ----
#pragma unroll
        for (int h = 0; h < 2; ++h) {
            f16x8 pa = *reinterpret_cast<const f16x8*>(&p_lds[w][h][lr][lg * 8]);
#pragma unroll
            for (int vd = 0; vd < 4; ++vd) {
                f16x8 bv = *reinterpret_cast<const f16x8*>(&vt_lds[h][vd * 16 + lr][lg * 8]);
                O[h][vd] = __builtin_amdgcn_mfma_f32_16x16x32_f16(pa, bv, O[h][vd], 0, 0, 0);
            }
        }
        __syncthreads();
    }
    // ---- epilogue: unnormalized O (f16) + row-sums l ----
#pragma unroll
    for (int r = 0; r < 4; ++r) {
        int q = q0 + lg * 4 + r;
#pragma unroll
        for (int h = 0; h < 2; ++h) {
            float ls = lsum[h][r];
#pragma unroll
            for (int m = 1; m < 16; m <<= 1) ls += __shfl_xor(ls, m, 64);
            size_t base = (((size_t)split * 2 + b) * 2 + h) * 4096 + q;
            if (lr == 0) l_ws[base] = ls;
#pragma unroll
            for (int vd = 0; vd < 4; ++vd)
                opart[base * 64 + vd * 16 + lr] = f2h(O[h][vd][r]);
        }
    }
}

// ---------------- combine the 8 key-splits: plain sum + divide ----------------
__global__ __launch_bounds__(256) void combine(const u16* __restrict__ opart,
                                               const float* __restrict__ l_ws,
                                               u16* __restrict__ attn_h) {
    int e = blockIdx.x * 256 + threadIdx.x;  // < 1048576
    int tok = e >> 7, d = e & 127;
    int b = tok >> 12, n = tok & 4095;
    int h = d >> 6, dh = d & 63;
    float O = 0.f, L = 0.f;
#pragma unroll
    for (int s = 0; s < 8; ++s) {
        size_t base = (((size_t)s * 2 + b) * 2 + h) * 4096 + n;
        O += h2f(opart[base * 64 + dh]);
        L += l_ws[base];
    }
    attn_h[(size_t)tok * 128 + d] = f2h(O / L);
}

// ---------------- FF GEMMs: [8192,128]@[128,128] (+gelu) ----------------
__global__ __launch_bounds__(256) void ff_gemm(const u16* __restrict__ in, const u16* __restrict__ w,
                                               const float* __restrict__ bias, void* __restrict__ out,
                                               int act) {
    int cg = blockIdx.x & 1;
    int tok0 = (blockIdx.x >> 1) * 64 + (threadIdx.x >> 6) * 16;
    int lane = threadIdx.x & 63, lr = lane & 15, lg = lane >> 4;
    f16x8 a[4];
#pragma unroll
    for (int ks = 0; ks < 4; ++ks)
        a[ks] = *reinterpret_cast<const f16x8*>(in + (size_t)(tok0 + lr) * 128 + ks * 32 + lg * 8);
#pragma unroll
    for (int ci = 0; ci < 4; ++ci) {
        int c = cg * 4 + ci;
        f32x4 acc = {0.f, 0.f, 0.f, 0.f};
#pragma unroll
        for (int ks = 0; ks < 4; ++ks) {
            f16x8 bw = *reinterpret_cast<const f16x8*>(w + (size_t)(c * 16 + lr) * 128 + ks * 32 + lg * 8);
            acc = __builtin_amdgcn_mfma_f32_16x16x32_f16(a[ks], bw, acc, 0, 0, 0);
        }
        int j = c * 16 + lr;
        float bv = bias[j];
#pragma unroll
        for (int r = 0; r < 4; ++r) {
            int tok = tok0 + lg * 4 + r;
            float val = acc[r] + bv;
            if (act) {
                float g = 0.5f * val * (1.f + erff(val * 0.7071067811865475f));
                ((u16*)out)[(size_t)tok * 128 + j] = f2h(g);
            } else {
                ((float*)out)[(size_t)tok * 128 + j] = val;
            }
        }
    }
}

extern "C" void kernel_launch(void* const* d_in, const int* in_sizes, int n_in,
                              void* d_out, int out_size, void* d_ws, size_t ws_size,
                              hipStream_t stream) {
    const float* x     = (const float*)d_in[0];
    const float* v_qkv = (const float*)d_in[1];
    const float* g_qkv = (const float*)d_in[2];
    const float* b_qkv = (const float*)d_in[3];
    const float* v_ff1 = (const float*)d_in[4];
    const float* g_ff1 = (const float*)d_in[5];
    const float* b_ff1 = (const float*)d_in[6];
    const float* v_ff2 = (const float*)d_in[7];
    const float* g_ff2 = (const float*)d_in[8];
    const float* b_ff2 = (const float*)d_in[9];

    char* w = (char*)d_ws;
    size_t off = 0;
    float* accum   = (float*)(w + off); off += 256;
    float* partial = (float*)(w + off); off += 2048 * 4;
    float* spa_tab = (float*)(w + off); off += (size_t)127 * 4096 * 4;     // 2.08 MB
    u16* xh      = (u16*)(w + off);   off += (size_t)8192 * 128 * 2;
    float* sqv   = (float*)(w + off); off += (size_t)8192 * 4;
    u16* wqkv    = (u16*)(w + off);   off += (size_t)384 * 128 * 2;
    u16* w1      = (u16*)(w + off);   off += (size_t)128 * 128 * 2;
    u16* w2      = (u16*)(w + off);   off += (size_t)128 * 128 * 2;
    u16* q_ws    = (u16*)(w + off);   off += (size_t)4 * 4096 * 64 * 2;
    u16* k_ws    = (u16*)(w + off);   off += (size_t)4 * 4096 * 64 * 2;
    u16* vt_ws   = (u16*)(w + off);   off += (size_t)4 * 4096 * 64 * 2;
    u16* opart   = (u16*)(w + off);   off += (size_t)32 * 4096 * 64 * 2;   // [split8][b2][h2][n][64] f16
    float* l_ws  = (float*)(w + off); off += (size_t)32 * 4096 * 4;        // [split8][b2][h2][n]
    u16* attn_h  = (u16*)(w + off);   off += (size_t)8192 * 128 * 2;
    u16* h1      = (u16*)(w + off);   off += (size_t)8192 * 128 * 2;

    // sigma_spa: exact closed form over grid-delta histogram (deterministic)
    double ssum = 0.0;
    for (int dx = -63; dx <= 63; ++dx) {
        int adx = dx < 0 ? -dx : dx;
        for (int dy = -63; dy <= 63; ++dy) {
            int ady = dy < 0 ? -dy : dy;
            ssum += (double)(64 - adx) * (double)(64 - ady) * sqrt((double)(dx * dx + dy * dy));
        }
    }
    float sigma_spa = (float)(ssum / (4096.0 * 4096.0));
    float c2 = 1.0f / (2.0f * sigma_spa * sigma_spa);

    hipMemsetAsync(w, 0, 256 + 2048 * 4, stream);   // accum + sigma partials

    prep_x<<<2048, 256, 0, stream>>>(x, xh, sqv);
    prep_w<<<640, 64, 0, stream>>>(v_qkv, g_qkv, v_ff1, g_ff1, v_ff2, g_ff2, wqkv, w1, w2);
    spa_tab_k<<<2032, 256, 0, stream>>>(spa_tab, c2);
    sigma_gemm<<<2048, 256, 0, stream>>>(xh, sqv, partial);
    sigma_fin<<<1, 256, 0, stream>>>(partial, accum);
    qkv_gemm<<<256, 256, 0, stream>>>(xh, wqkv, b_qkv, q_ws, k_ws, vt_ws);
    attn_fused<<<1024, 256, 0, stream>>>(xh, sqv, q_ws, k_ws, vt_ws, accum, spa_tab, opart, l_ws);
    combine<<<4096, 256, 0, stream>>>(opart, l_ws, attn_h);
    ff_gemm<<<256, 256, 0, stream>>>(attn_h, w1, b_ff1, (void*)h1, 1);
    ff_gemm<<<256, 256, 0, stream>>>(h1, w2, b_ff2, d_out, 0);
}